// Round 12
// baseline (364.002 us; speedup 1.0000x reference)
//
#include <hip/hip_runtime.h>
#include <stdint.h>

typedef unsigned short u16;
typedef u16 u16x8 __attribute__((ext_vector_type(8)));
typedef u16 u16x4 __attribute__((ext_vector_type(4)));
typedef __bf16 bf16x8 __attribute__((ext_vector_type(8)));
typedef float f32x4 __attribute__((ext_vector_type(4)));

#define DEV static __device__ __forceinline__

DEV u16 f2bf(float f) {
  union { float f; uint32_t u; } v; v.f = f;
  uint32_t r = v.u + 0x7FFFu + ((v.u >> 16) & 1u);
  return (u16)(r >> 16);
}
DEV float bf2f(u16 s) {
  union { uint32_t u; float f; } v; v.u = ((uint32_t)s) << 16;
  return v.f;
}
DEV float elu1(float x) { return x > 0.f ? x + 1.f : __expf(x); }
DEV u16x8 ld8u(const u16* p) { return *reinterpret_cast<const u16x8*>(p); }

DEV f32x4 mfma16(u16x8 a, u16x8 b, f32x4 c) {
  return __builtin_amdgcn_mfma_f32_16x16x32_bf16(
      __builtin_bit_cast(bf16x8, a), __builtin_bit_cast(bf16x8, b), c, 0, 0, 0);
}
DEV void async16(void* lds, const void* g) {
  __builtin_amdgcn_global_load_lds(
      (__attribute__((address_space(1))) void*)g,
      (__attribute__((address_space(3))) void*)lds, 16, 0, 0);
}

#define BARR __builtin_amdgcn_s_barrier()
#define LG0  asm volatile("s_waitcnt lgkmcnt(0)" ::: "memory")
#define VMC(N) asm volatile("s_waitcnt vmcnt(" #N ")" ::: "memory")

// ---------------- prep kernels ----------------

__global__ __launch_bounds__(256) void k_cvt(const float* __restrict__ in, u16* __restrict__ out) {
  int i = blockIdx.x * 256 + threadIdx.x;
  const float4* p = reinterpret_cast<const float4*>(in) + (size_t)i * 2;
  float4 a = p[0], b = p[1];
  u16x8 o;
  o[0] = f2bf(a.x); o[1] = f2bf(a.y); o[2] = f2bf(a.z); o[3] = f2bf(a.w);
  o[4] = f2bf(b.x); o[5] = f2bf(b.y); o[6] = f2bf(b.z); o[7] = f2bf(b.w);
  reinterpret_cast<u16x8*>(out)[i] = o;
}

__global__ __launch_bounds__(1024) void k_tr(const float* __restrict__ Wq, const float* __restrict__ Wk,
                                             const float* __restrict__ Wv, const float* __restrict__ Wo,
                                             u16* __restrict__ wt, u16* __restrict__ wot) {
  __shared__ float tb[32][33];
  int mat = blockIdx.x >> 10;
  int tile = blockIdx.x & 1023;
  int n0 = (tile >> 5) * 32;
  int k0 = (tile & 31) * 32;
  const float* W = (mat == 0) ? Wq : (mat == 1) ? Wk : (mat == 2) ? Wv : Wo;
  int tx = threadIdx.x & 31, ty = threadIdx.x >> 5;
  tb[ty][tx] = W[(size_t)(k0 + ty) * 1024 + n0 + tx];
  __syncthreads();
  u16 v = f2bf(tb[tx][ty]);
  if (mat < 3) wt[(size_t)(mat * 1024 + n0 + ty) * 1024 + k0 + tx] = v;
  else         wot[(size_t)(n0 + ty) * 1024 + k0 + tx] = v;
}

__global__ void k_bias(const float* __restrict__ rel, float* __restrict__ bias) {
  int off = blockIdx.x * 256 + threadIdx.x;
  if (off >= 1023) return;
  int rp = off - 511;
  int bck = rp > 0 ? 16 : 0;
  int arp = rp < 0 ? -rp : rp;
  int idx;
  if (arp < 8) idx = arp;
  else {
    float l = logf((float)arp * 0.125f) / logf(16.0f) * 8.0f;
    int lg = 8 + (int)l;
    idx = lg < 15 ? lg : 15;
  }
  bck += idx;
  for (int h = 0; h < 16; ++h) bias[h * 1023 + off] = rel[bck * 16 + h];
}

// ---------------- 256x256 multi-block MFMA GEMM ----------------
// BM=BN=256, BK=32, 8 waves (2M x 4N, per-wave 128x64), dbuf LDS 64 KiB ->
// 2 blocks/CU co-resident (m114 overlap) at the staging-minimal 256 tile
// ((BM+BN)/(BM*BN) per-FLOP staging is half of 128x256's). Superrow-
// interleaved LDS layout (proven 0-conflict in R8); counted vmcnt(4);
// L2 squares (4m x 4n). acc[8][4]=128 VGPR; (512,2) caps at 256 (no spill).

template <int EPI, int NSQN>   // NSQN = n-groups of 4 tiles (GEMM1: 3, GEMM2: 1)
__global__ __launch_bounds__(512, 2) void k_g256(const u16* __restrict__ A, const u16* __restrict__ Bt,
                                                 u16* __restrict__ oq, u16* __restrict__ ok2,
                                                 u16* __restrict__ ovt, float* __restrict__ of) {
  __shared__ __align__(16) u16 lsA[2][256 * 32];
  __shared__ __align__(16) u16 lsB[2][256 * 32];
  const int t = threadIdx.x;
  const int lane = t & 63, w = t >> 6;
  const int wm = w >> 2, wn = w & 3;
  const int lr = lane & 15, lg = lane >> 4;

  // XCD chunk -> 4m x 4n L2 squares
  const int bid = blockIdx.x;
  const int xcd = bid & 7, local = bid >> 3;
  const int s = local >> 4, w16 = local & 15;
  const int m0 = (xcd * 8 + (s / NSQN) * 4 + (w16 >> 2)) * 256;
  const int n0 = ((s % NSQN) * 4 + (w16 & 3)) * 256;

  // stage: chunk c -> lds offset c*16B (linear dest). Chunk c holds
  // (row = 2S + (q>>2), kunit = q&3) with S=c>>3, q=(c&7)^(S&7).
  auto stage = [&](int kt, int slot) {
    const int k0 = kt * 32;
#pragma unroll
    for (int i = 0; i < 2; ++i) {
      int c = i * 512 + t, S = c >> 3, q = (c & 7) ^ (S & 7);
      int row = 2 * S + (q >> 2), u = q & 3;
      async16(&lsA[slot][c * 8], A + (size_t)(m0 + row) * 1024 + k0 + u * 8);
    }
#pragma unroll
    for (int i = 0; i < 2; ++i) {
      int c = i * 512 + t, S = c >> 3, q = (c & 7) ^ (S & 7);
      int row = 2 * S + (q >> 2), u = q & 3;
      async16(&lsB[slot][c * 8], Bt + (size_t)(n0 + row) * 1024 + k0 + u * 8);
    }
  };
  // frag read: row r_, kunit lg -> superrow r_>>1, slot ((r_&1)*4+lg)^(sr&7)
  auto rdoff = [&](int r_) -> int {
    return (r_ >> 1) * 64 + (((((r_ & 1) << 2) + lg) ^ ((r_ >> 1) & 7)) << 3);
  };

  f32x4 acc[8][4];
#pragma unroll
  for (int i = 0; i < 8; ++i)
#pragma unroll
    for (int j = 0; j < 4; ++j) acc[i][j] = (f32x4){0.f, 0.f, 0.f, 0.f};

  stage(0, 0);
  stage(1, 1);
  VMC(4);  // tile 0 landed; tile 1 in flight
  BARR;

  for (int kt = 0; kt < 32; ++kt) {
    const int slot = kt & 1;
    const u16* la = &lsA[slot][0];
    const u16* lb = &lsB[slot][0];

    u16x8 af[8], bf[4];
#pragma unroll
    for (int mi = 0; mi < 8; ++mi) af[mi] = ld8u(la + rdoff(wm * 128 + mi * 16 + lr));
#pragma unroll
    for (int ni = 0; ni < 4; ++ni) bf[ni] = ld8u(lb + rdoff(wn * 64 + ni * 16 + lr));
    LG0;   // my slot reads retired (regs valid)
    BARR;  // all waves done reading slot -> safe to overwrite
    if (kt + 2 < 32) stage(kt + 2, slot);

    __builtin_amdgcn_s_setprio(1);
#pragma unroll
    for (int mi = 0; mi < 8; ++mi)
#pragma unroll
      for (int ni = 0; ni < 4; ++ni)
        acc[mi][ni] = mfma16(af[mi], bf[ni], acc[mi][ni]);
    __builtin_amdgcn_s_setprio(0);

    if (kt + 2 < 32)      { VMC(4); }  // tile kt+1 landed; kt+2 in flight
    else if (kt == 30)    { VMC(0); }  // drain tile 31
    BARR;
  }

  if (EPI == 0) {
    const int which = n0 >> 10;
    const int nb = (n0 & 1023) + wn * 64;
#pragma unroll
    for (int mi = 0; mi < 8; ++mi)
#pragma unroll
      for (int r = 0; r < 4; ++r) {
        int m = m0 + wm * 128 + mi * 16 + lg * 4 + r;
        int b = m >> 9, s2 = m & 511;
#pragma unroll
        for (int ni = 0; ni < 4; ++ni) {
          int nc = nb + ni * 16 + lr;
          int h = nc >> 6, d = nc & 63;
          int bh = b * 16 + h;
          u16 v = f2bf(acc[mi][ni][r]);
          if (which == 0)      oq[(size_t)(bh * 512 + s2) * 64 + d] = v;
          else if (which == 1) ok2[(size_t)(bh * 512 + s2) * 64 + d] = v;
          else                 ovt[(size_t)(bh * 64 + d) * 512 + s2] = v;
        }
      }
  } else {
#pragma unroll
    for (int mi = 0; mi < 8; ++mi)
#pragma unroll
      for (int r = 0; r < 4; ++r) {
        int m = m0 + wm * 128 + mi * 16 + lg * 4 + r;
#pragma unroll
        for (int ni = 0; ni < 4; ++ni) {
          int n = n0 + wn * 64 + ni * 16 + lr;
          of[(size_t)m * 1024 + n] = acc[mi][ni][r];
        }
      }
  }
}

// ---------------- compressive memory (MFMA): M = sk^T @ v per (g,h,c) ----------------

__global__ __launch_bounds__(256) void k_mem(const u16* __restrict__ K, const u16* __restrict__ Vt,
                                             float* __restrict__ Mp, float* __restrict__ zp) {
  __shared__ __align__(16) u16 skT[64 * 128];
  __shared__ __align__(16) u16 lV[64 * 128];
  __shared__ float mbuf[64][65];
  __shared__ float zsh[4][64];
  const int bid = blockIdx.x;
  const int g = bid >> 7, h = (bid >> 3) & 15, c = bid & 7;
  const int bh = (g * 8 + c) * 16 + h;
  const u16* kp = K + (size_t)bh * 512 * 64;
  const u16* vp = Vt + (size_t)bh * 64 * 512;
  const int t = threadIdx.x, lane = t & 63, w = t >> 6;
  const int lr = lane & 15, lg = lane >> 4;
  const int dmy = t & 63, sq = t >> 6;

  f32x4 acc[4][4];
#pragma unroll
  for (int i = 0; i < 4; ++i)
#pragma unroll
    for (int j = 0; j < 4; ++j) acc[i][j] = (f32x4){0.f, 0.f, 0.f, 0.f};
  float zacc = 0.f;

  for (int s0 = 0; s0 < 512; s0 += 128) {
#pragma unroll
    for (int i = 0; i < 4; ++i) {
      int c2 = i * 256 + t;
      int row = c2 >> 4, u = c2 & 15;
      async16(lV + c2 * 8, vp + (size_t)row * 512 + s0 + ((u ^ (row & 7)) << 3));
    }
#pragma unroll
    for (int r = 0; r < 4; ++r) {
      const int un = sq + r * 4;
      const int ss0 = un * 8;
      u16x8 vals;
#pragma unroll
      for (int j = 0; j < 8; ++j) {
        float x = elu1(bf2f(kp[(size_t)(s0 + ss0 + j) * 64 + dmy]));
        zacc += x;
        vals[j] = f2bf(x);
      }
      *reinterpret_cast<u16x8*>(skT + dmy * 128 + ((un ^ (dmy & 7)) << 3)) = vals;
    }
    VMC(0);
    __syncthreads();
    u16x8 af[4], bfv[4];
#pragma unroll
    for (int ds = 0; ds < 4; ++ds) {
      const int d = ds * 16 + lr;
      af[ds] = ld8u(skT + d * 128 + (((w * 4 + lg) ^ (d & 7)) << 3));
    }
#pragma unroll
    for (int es = 0; es < 4; ++es) {
      const int e = es * 16 + lr;
      bfv[es] = ld8u(lV + e * 128 + (((w * 4 + lg) ^ (e & 7)) << 3));
    }
#pragma unroll
    for (int ds = 0; ds < 4; ++ds)
#pragma unroll
      for (int es = 0; es < 4; ++es) acc[ds][es] = mfma16(af[ds], bfv[es], acc[ds][es]);
    __syncthreads();
  }

  zsh[sq][dmy] = zacc;
  for (int wv = 0; wv < 4; ++wv) {
    if (w == wv) {
#pragma unroll
      for (int ds = 0; ds < 4; ++ds)
#pragma unroll
        for (int es = 0; es < 4; ++es)
#pragma unroll
          for (int r = 0; r < 4; ++r) {
            int d = ds * 16 + lg * 4 + r, e = es * 16 + lr;
            if (wv == 0) mbuf[d][e] = acc[ds][es][r];
            else         mbuf[d][e] += acc[ds][es][r];
          }
    }
    __syncthreads();
  }
#pragma unroll
  for (int j = 0; j < 16; ++j) {
    int idx = j * 256 + t;
    Mp[(size_t)bid * 4096 + idx] = mbuf[idx >> 6][idx & 63];
  }
  if (t < 64) zp[(size_t)bid * 64 + t] = zsh[0][t] + zsh[1][t] + zsh[2][t] + zsh[3][t];
}

__global__ __launch_bounds__(256) void k_red(const float* __restrict__ Mp, const float* __restrict__ zp,
                                             u16* __restrict__ Mt, float* __restrict__ zv) {
  const int gh = blockIdx.x;
  const int t = threadIdx.x;
#pragma unroll
  for (int j = 0; j < 16; ++j) {
    int idx = j * 256 + t;
    int d = idx >> 6, e = idx & 63;
    float s = 0.f;
#pragma unroll
    for (int c = 0; c < 8; ++c) s += Mp[(size_t)(gh * 8 + c) * 4096 + idx];
    Mt[(size_t)gh * 4096 + e * 64 + d] = f2bf(s);
  }
  if (t < 64) {
    float s = 0.f;
#pragma unroll
    for (int c = 0; c < 8; ++c) s += zp[(size_t)(gh * 8 + c) * 64 + t];
    zv[gh * 64 + t] = s;
  }
}

// ---------------- fused attention: dbuf K/V, counted vmcnt prefetch ----------------

__global__ __launch_bounds__(256, 3) void k_attn(const u16* __restrict__ Q, const u16* __restrict__ K,
                                                 const u16* __restrict__ Vt, const u16* __restrict__ Mt,
                                                 const float* __restrict__ zv, const float* __restrict__ bias,
                                                 const float* __restrict__ beta, u16* __restrict__ blend) {
  __shared__ __align__(16) u16 lK[2][64 * 64];
  __shared__ __align__(16) u16 lV[2][64 * 64];
  __shared__ __align__(16) u16 ps[4][32 * 64];
  __shared__ float lbias[640];
  __shared__ float zs[64];
  __shared__ float rsl[4][32];
  __shared__ float dnl[4][32];

  const int bid = blockIdx.x;
  const int bh = bid >> 2, qg = bid & 3;
  const int b = bh >> 4, h = bh & 15, g = b >> 3;
  const int gh = g * 16 + h;
  const int t = threadIdx.x, lane = t & 63, w = t >> 6;
  const int lr = lane & 15, lg = lane >> 4;
  const int q0w = qg * 128 + w * 32;
  const u16* qp = Q + (size_t)bh * 512 * 64;
  const u16* kp = K + (size_t)bh * 512 * 64;
  const u16* vp = Vt + (size_t)bh * 64 * 512;
  const u16* mp = Mt + (size_t)gh * 4096;
  const float gate = 1.f / (1.f + __expf(-beta[h]));
  u16* psw = &ps[w][0];

  auto stage = [&](int kt, int sl) {
#pragma unroll
    for (int i = 0; i < 2; ++i) {
      int c = w * 128 + i * 64 + lane;
      int kr = c >> 3, u = c & 7;
      async16(&lK[sl][c * 8], kp + (size_t)(kt * 64 + kr) * 64 + ((u ^ (kr & 7)) << 3));
      async16(&lV[sl][c * 8], vp + (size_t)kr * 512 + kt * 64 + ((u ^ (kr & 7)) << 3));
    }
  };

  for (int i = t; i < 640; i += 256) lbias[i] = bias[h * 1023 + i + 384 - qg * 128];
  if (t < 64) zs[t] = zv[gh * 64 + t];
  LG0; BARR;

  u16x8 qf[2][2];
#pragma unroll
  for (int qs = 0; qs < 2; ++qs)
#pragma unroll
    for (int dc = 0; dc < 2; ++dc)
      qf[qs][dc] = ld8u(qp + (size_t)(q0w + qs * 16 + lr) * 64 + dc * 32 + lg * 8);

#pragma unroll
  for (int qs = 0; qs < 2; ++qs) {
    float sum = 0.f;
#pragma unroll
    for (int dc = 0; dc < 2; ++dc)
#pragma unroll
      for (int j = 0; j < 8; ++j)
        sum += elu1(bf2f(qf[qs][dc][j])) * zs[dc * 32 + lg * 8 + j];
    sum += __shfl_xor(sum, 16, 64);
    sum += __shfl_xor(sum, 32, 64);
    if (lane < 16) dnl[w][qs * 16 + lane] = sum + 1e-6f;
  }

  stage(0, 0);

  f32x4 acc[2][4];
#pragma unroll
  for (int qs = 0; qs < 2; ++qs)
#pragma unroll
    for (int es = 0; es < 4; ++es) acc[qs][es] = (f32x4){0.f, 0.f, 0.f, 0.f};
  float rs[2] = {0.f, 0.f};

  for (int kt = 0; kt < 8; ++kt) {
    const int sl = kt & 1;
    if (kt + 1 < 8) stage(kt + 1, sl ^ 1);
    if (kt + 1 < 8) { VMC(4); } else { VMC(0); }
    BARR;

#pragma unroll
    for (int ks = 0; ks < 4; ++ks) {
      const int kr = ks * 16 + lr;
      u16x8 kf0 = ld8u(&lK[sl][kr * 64 + (((0 * 4 + lg) ^ (kr & 7)) << 3)]);
      u16x8 kf1 = ld8u(&lK[sl][kr * 64 + (((1 * 4 + lg) ^ (kr & 7)) << 3)]);
#pragma unroll
      for (int qs = 0; qs < 2; ++qs) {
        f32x4 s = mfma16(kf0, qf[qs][0], (f32x4){0.f, 0.f, 0.f, 0.f});
        s = mfma16(kf1, qf[qs][1], s);
        const int bb = kt * 64 + ks * 16 + lg * 4 - (w * 32 + qs * 16 + lr) + 127;
        u16x4 pk;
        float lsum = 0.f;
#pragma unroll
        for (int r = 0; r < 4; ++r) {
          float p = __expf(s[r] + lbias[bb + r]);
          lsum += p;
          pk[r] = f2bf(p);
        }
        rs[qs] += lsum;
        const int row = qs * 16 + lr;
        const int addr = row * 64 + (((ks * 2 + (lg >> 1)) ^ (row & 7)) << 3) + (lg & 1) * 4;
        *reinterpret_cast<u16x4*>(psw + addr) = pk;
      }
    }
#pragma unroll
    for (int kc = 0; kc < 2; ++kc) {
      u16x8 pf[2];
#pragma unroll
      for (int qs = 0; qs < 2; ++qs) {
        const int row = qs * 16 + lr;
        pf[qs] = ld8u(psw + row * 64 + (((kc * 4 + lg) ^ (row & 7)) << 3));
      }
#pragma unroll
      for (int es = 0; es < 4; ++es) {
        const int er = es * 16 + lr;
        u16x8 vf = ld8u(&lV[sl][er * 64 + (((kc * 4 + lg) ^ (er & 7)) << 3)]);
#pragma unroll
        for (int qs = 0; qs < 2; ++qs) acc[qs][es] = mfma16(pf[qs], vf, acc[qs][es]);
      }
    }
    BARR;
  }

#pragma unroll
  for (int qs = 0; qs < 2; ++qs) {
    float v = rs[qs];
    v += __shfl_xor(v, 16, 64);
    v += __shfl_xor(v, 32, 64);
    if (lane < 16) rsl[w][qs * 16 + lane] = 1.f / v;
  }

  u16x8 sqf[2][2];
#pragma unroll
  for (int qs = 0; qs < 2; ++qs)
#pragma unroll
    for (int dc = 0; dc < 2; ++dc)
#pragma unroll
      for (int j = 0; j < 8; ++j) sqf[qs][dc][j] = f2bf(elu1(bf2f(qf[qs][dc][j])));
  f32x4 am[2][4];
#pragma unroll
  for (int qs = 0; qs < 2; ++qs)
#pragma unroll
    for (int es = 0; es < 4; ++es) am[qs][es] = (f32x4){0.f, 0.f, 0.f, 0.f};
#pragma unroll
  for (int es = 0; es < 4; ++es)
#pragma unroll
    for (int dc = 0; dc < 2; ++dc) {
      u16x8 mf = ld8u(mp + (es * 16 + lr) * 64 + dc * 32 + lg * 8);
#pragma unroll
      for (int qs = 0; qs < 2; ++qs) am[qs][es] = mfma16(sqf[qs][dc], mf, am[qs][es]);
    }

#pragma unroll
  for (int qs = 0; qs < 2; ++qs)
#pragma unroll
    for (int r = 0; r < 4; ++r) {
      const int rowl = qs * 16 + lg * 4 + r;
      const float rinv = rsl[w][rowl];
      const float den = dnl[w][rowl];
      const int q = q0w + rowl;
#pragma unroll
      for (int es = 0; es < 4; ++es) {
        float o = gate * (am[qs][es][r] / den) + (1.f - gate) * acc[qs][es][r] * rinv;
        blend[(size_t)(b * 512 + q) * 1024 + h * 64 + es * 16 + lr] = f2bf(o);
      }
    }
}

// ---------------- launch ----------------

extern "C" void kernel_launch(void* const* d_in, const int* in_sizes, int n_in,
                              void* d_out, int out_size, void* d_ws, size_t ws_size,
                              hipStream_t stream) {
  (void)in_sizes; (void)n_in; (void)out_size; (void)ws_size;
  const float* hs   = (const float*)d_in[0];
  const float* Wq   = (const float*)d_in[1];
  const float* Wk   = (const float*)d_in[2];
  const float* Wv   = (const float*)d_in[3];
  const float* Wo   = (const float*)d_in[4];
  const float* rel  = (const float*)d_in[5];
  const float* beta = (const float*)d_in[6];
  float* out = (float*)d_out;

  char* ws = (char*)d_ws;
  size_t off = 0;
  auto alloc = [&](size_t bytes) -> char* {
    char* p = ws + off;
    off += (bytes + 255) & ~(size_t)255;
    return p;
  };
  u16* hsb    = (u16*)alloc(16384ull * 1024 * 2);  // reused as blend after GEMM1
  u16* wt     = (u16*)alloc(3072ull * 1024 * 2);
  u16* wot    = (u16*)alloc(1024ull * 1024 * 2);
  u16* q      = (u16*)alloc(16384ull * 1024 * 2);
  u16* k      = (u16*)alloc(16384ull * 1024 * 2);
  u16* vt     = (u16*)alloc(16384ull * 1024 * 2);
  float* Mp   = (float*)alloc(512ull * 4096 * 4);
  float* zp   = (float*)alloc(512ull * 64 * 4);
  u16* Mt     = (u16*)alloc(64ull * 4096 * 2);
  float* zv   = (float*)alloc(64ull * 64 * 4);
  float* bias = (float*)alloc(16ull * 1023 * 4);
  u16* blend  = hsb;

  k_cvt<<<8192, 256, 0, stream>>>(hs, hsb);
  k_tr<<<4096, 1024, 0, stream>>>(Wq, Wk, Wv, Wo, wt, wot);
  k_bias<<<4, 256, 0, stream>>>(rel, bias);
  // GEMM1: 64 m-tiles x 12 n-tiles = 768 blocks; 4x4 L2 squares, 3 n-groups
  k_g256<0, 3><<<768, 512, 0, stream>>>(hsb, wt, q, k, vt, nullptr);
  k_mem<<<512, 256, 0, stream>>>(k, vt, Mp, zp);
  k_red<<<64, 256, 0, stream>>>(Mp, zp, Mt, zv);
  k_attn<<<2048, 256, 0, stream>>>(q, k, vt, Mt, zv, bias, beta, blend);
  // GEMM2: 64 m-tiles x 4 n-tiles = 256 blocks; 1 n-group
  k_g256<1, 1><<<256, 512, 0, stream>>>(blend, wot, nullptr, nullptr, nullptr, out);
}

// Round 14
// 332.728 us; speedup vs baseline: 1.0940x; 1.0940x over previous
//
#include <hip/hip_runtime.h>
#include <stdint.h>

typedef unsigned short u16;
typedef u16 u16x8 __attribute__((ext_vector_type(8)));
typedef u16 u16x4 __attribute__((ext_vector_type(4)));
typedef __bf16 bf16x8 __attribute__((ext_vector_type(8)));
typedef float f32x4 __attribute__((ext_vector_type(4)));

#define DEV static __device__ __forceinline__

DEV u16 f2bf(float f) {
  union { float f; uint32_t u; } v; v.f = f;
  uint32_t r = v.u + 0x7FFFu + ((v.u >> 16) & 1u);
  return (u16)(r >> 16);
}
DEV float bf2f(u16 s) {
  union { uint32_t u; float f; } v; v.u = ((uint32_t)s) << 16;
  return v.f;
}
DEV float elu1(float x) { return x > 0.f ? x + 1.f : __expf(x); }
DEV u16x8 ld8u(const u16* p) { return *reinterpret_cast<const u16x8*>(p); }

DEV f32x4 mfma16(u16x8 a, u16x8 b, f32x4 c) {
  return __builtin_amdgcn_mfma_f32_16x16x32_bf16(
      __builtin_bit_cast(bf16x8, a), __builtin_bit_cast(bf16x8, b), c, 0, 0, 0);
}
DEV void async16(void* lds, const void* g) {
  __builtin_amdgcn_global_load_lds(
      (__attribute__((address_space(1))) void*)g,
      (__attribute__((address_space(3))) void*)lds, 16, 0, 0);
}

#define BARR __builtin_amdgcn_s_barrier()
#define LG0  asm volatile("s_waitcnt lgkmcnt(0)" ::: "memory")
#define VMC(N) asm volatile("s_waitcnt vmcnt(" #N ")" ::: "memory")

// ---------------- prep kernels ----------------

__global__ __launch_bounds__(256) void k_cvt(const float* __restrict__ in, u16* __restrict__ out) {
  int i = blockIdx.x * 256 + threadIdx.x;
  const float4* p = reinterpret_cast<const float4*>(in) + (size_t)i * 2;
  float4 a = p[0], b = p[1];
  u16x8 o;
  o[0] = f2bf(a.x); o[1] = f2bf(a.y); o[2] = f2bf(a.z); o[3] = f2bf(a.w);
  o[4] = f2bf(b.x); o[5] = f2bf(b.y); o[6] = f2bf(b.z); o[7] = f2bf(b.w);
  reinterpret_cast<u16x8*>(out)[i] = o;
}

__global__ __launch_bounds__(1024) void k_tr(const float* __restrict__ Wq, const float* __restrict__ Wk,
                                             const float* __restrict__ Wv, const float* __restrict__ Wo,
                                             u16* __restrict__ wt, u16* __restrict__ wot) {
  __shared__ float tb[32][33];
  int mat = blockIdx.x >> 10;
  int tile = blockIdx.x & 1023;
  int n0 = (tile >> 5) * 32;
  int k0 = (tile & 31) * 32;
  const float* W = (mat == 0) ? Wq : (mat == 1) ? Wk : (mat == 2) ? Wv : Wo;
  int tx = threadIdx.x & 31, ty = threadIdx.x >> 5;
  tb[ty][tx] = W[(size_t)(k0 + ty) * 1024 + n0 + tx];
  __syncthreads();
  u16 v = f2bf(tb[tx][ty]);
  if (mat < 3) wt[(size_t)(mat * 1024 + n0 + ty) * 1024 + k0 + tx] = v;
  else         wot[(size_t)(n0 + ty) * 1024 + k0 + tx] = v;
}

__global__ void k_bias(const float* __restrict__ rel, float* __restrict__ bias) {
  int off = blockIdx.x * 256 + threadIdx.x;
  if (off >= 1023) return;
  int rp = off - 511;
  int bck = rp > 0 ? 16 : 0;
  int arp = rp < 0 ? -rp : rp;
  int idx;
  if (arp < 8) idx = arp;
  else {
    float l = logf((float)arp * 0.125f) / logf(16.0f) * 8.0f;
    int lg = 8 + (int)l;
    idx = lg < 15 ? lg : 15;
  }
  bck += idx;
  for (int h = 0; h < 16; ++h) bias[h * 1023 + off] = rel[bck * 16 + h];
}

// ---------------- 128x256 multi-block MFMA GEMM (R8/R11 core — best measured) ----------------
// BM=128, BN=256, BK=32, 8 waves (2M x 4N), dbuf LDS 48 KiB, 3 blocks/CU.
// Superrow-interleaved LDS layout (0 conflicts); counted vmcnt(3); L2 squares.

template <int EPI>
__global__ __launch_bounds__(512, 3) void k_g256(const u16* __restrict__ A, const u16* __restrict__ Bt,
                                                 u16* __restrict__ oq, u16* __restrict__ ok2,
                                                 u16* __restrict__ ovt, float* __restrict__ of) {
  __shared__ __align__(16) u16 lsA[2][128 * 32];
  __shared__ __align__(16) u16 lsB[2][256 * 32];
  const int t = threadIdx.x;
  const int lane = t & 63, w = t >> 6;
  const int wm = w >> 2, wn = w & 3;
  const int lr = lane & 15, lg = lane >> 4;

  const int bid = blockIdx.x;
  const int xcd = bid & 7, local = bid >> 3;
  const int s = local >> 4, w16 = local & 15;
  const int msq = s & 3, nsq = s >> 2;
  const int m0 = (xcd * 16 + msq * 4 + (w16 >> 2)) * 128;
  const int n0 = (nsq * 4 + (w16 & 3)) * 256;

  auto stage = [&](int kt, int slot) {
    const int k0 = kt * 32;
    {
      int c = t, S = c >> 3, q = (c & 7) ^ (S & 7);
      int row = 2 * S + (q >> 2), u = q & 3;
      async16(&lsA[slot][c * 8], A + (size_t)(m0 + row) * 1024 + k0 + u * 8);
    }
#pragma unroll
    for (int i = 0; i < 2; ++i) {
      int c = i * 512 + t, S = c >> 3, q = (c & 7) ^ (S & 7);
      int row = 2 * S + (q >> 2), u = q & 3;
      async16(&lsB[slot][c * 8], Bt + (size_t)(n0 + row) * 1024 + k0 + u * 8);
    }
  };
  auto rdoff = [&](int r_) -> int {
    return (r_ >> 1) * 64 + (((((r_ & 1) << 2) + lg) ^ ((r_ >> 1) & 7)) << 3);
  };

  f32x4 acc[4][4];
#pragma unroll
  for (int i = 0; i < 4; ++i)
#pragma unroll
    for (int j = 0; j < 4; ++j) acc[i][j] = (f32x4){0.f, 0.f, 0.f, 0.f};

  stage(0, 0);
  stage(1, 1);
  VMC(3);
  BARR;

  for (int kt = 0; kt < 32; ++kt) {
    const int slot = kt & 1;
    const u16* la = &lsA[slot][0];
    const u16* lb = &lsB[slot][0];

    u16x8 af[4], bf[4];
#pragma unroll
    for (int mi = 0; mi < 4; ++mi) af[mi] = ld8u(la + rdoff(wm * 64 + mi * 16 + lr));
#pragma unroll
    for (int ni = 0; ni < 4; ++ni) bf[ni] = ld8u(lb + rdoff(wn * 64 + ni * 16 + lr));
    LG0;
    BARR;
    if (kt + 2 < 32) stage(kt + 2, slot);

    __builtin_amdgcn_s_setprio(1);
#pragma unroll
    for (int mi = 0; mi < 4; ++mi)
#pragma unroll
      for (int ni = 0; ni < 4; ++ni)
        acc[mi][ni] = mfma16(af[mi], bf[ni], acc[mi][ni]);
    __builtin_amdgcn_s_setprio(0);

    if (kt + 2 < 32)      { VMC(3); }
    else if (kt == 30)    { VMC(0); }
    BARR;
  }

  if (EPI == 0) {
    const int which = n0 >> 10;
    const int nb = (n0 & 1023) + wn * 64;
#pragma unroll
    for (int mi = 0; mi < 4; ++mi)
#pragma unroll
      for (int r = 0; r < 4; ++r) {
        int m = m0 + wm * 64 + mi * 16 + lg * 4 + r;
        int b = m >> 9, s2 = m & 511;
#pragma unroll
        for (int ni = 0; ni < 4; ++ni) {
          int nc = nb + ni * 16 + lr;
          int h = nc >> 6, d = nc & 63;
          int bh = b * 16 + h;
          u16 v = f2bf(acc[mi][ni][r]);
          if (which == 0)      oq[(size_t)(bh * 512 + s2) * 64 + d] = v;
          else if (which == 1) ok2[(size_t)(bh * 512 + s2) * 64 + d] = v;
          else                 ovt[(size_t)(bh * 64 + d) * 512 + s2] = v;
        }
      }
  } else {
#pragma unroll
    for (int mi = 0; mi < 4; ++mi)
#pragma unroll
      for (int r = 0; r < 4; ++r) {
        int m = m0 + wm * 64 + mi * 16 + lg * 4 + r;
#pragma unroll
        for (int ni = 0; ni < 4; ++ni) {
          int n = n0 + wn * 64 + ni * 16 + lr;
          of[(size_t)m * 1024 + n] = acc[mi][ni][r];
        }
      }
  }
}

// ---------------- compressive memory (MFMA): M = sk^T @ v per (g,h,c) ----------------

__global__ __launch_bounds__(256) void k_mem(const u16* __restrict__ K, const u16* __restrict__ Vt,
                                             float* __restrict__ Mp, float* __restrict__ zp) {
  __shared__ __align__(16) u16 skT[64 * 128];
  __shared__ __align__(16) u16 lV[64 * 128];
  __shared__ float mbuf[64][65];
  __shared__ float zsh[4][64];
  const int bid = blockIdx.x;
  const int g = bid >> 7, h = (bid >> 3) & 15, c = bid & 7;
  const int bh = (g * 8 + c) * 16 + h;
  const u16* kp = K + (size_t)bh * 512 * 64;
  const u16* vp = Vt + (size_t)bh * 64 * 512;
  const int t = threadIdx.x, lane = t & 63, w = t >> 6;
  const int lr = lane & 15, lg = lane >> 4;
  const int dmy = t & 63, sq = t >> 6;

  f32x4 acc[4][4];
#pragma unroll
  for (int i = 0; i < 4; ++i)
#pragma unroll
    for (int j = 0; j < 4; ++j) acc[i][j] = (f32x4){0.f, 0.f, 0.f, 0.f};
  float zacc = 0.f;

  for (int s0 = 0; s0 < 512; s0 += 128) {
#pragma unroll
    for (int i = 0; i < 4; ++i) {
      int c2 = i * 256 + t;
      int row = c2 >> 4, u = c2 & 15;
      async16(lV + c2 * 8, vp + (size_t)row * 512 + s0 + ((u ^ (row & 7)) << 3));
    }
#pragma unroll
    for (int r = 0; r < 4; ++r) {
      const int un = sq + r * 4;
      const int ss0 = un * 8;
      u16x8 vals;
#pragma unroll
      for (int j = 0; j < 8; ++j) {
        float x = elu1(bf2f(kp[(size_t)(s0 + ss0 + j) * 64 + dmy]));
        zacc += x;
        vals[j] = f2bf(x);
      }
      *reinterpret_cast<u16x8*>(skT + dmy * 128 + ((un ^ (dmy & 7)) << 3)) = vals;
    }
    VMC(0);
    __syncthreads();
    u16x8 af[4], bfv[4];
#pragma unroll
    for (int ds = 0; ds < 4; ++ds) {
      const int d = ds * 16 + lr;
      af[ds] = ld8u(skT + d * 128 + (((w * 4 + lg) ^ (d & 7)) << 3));
    }
#pragma unroll
    for (int es = 0; es < 4; ++es) {
      const int e = es * 16 + lr;
      bfv[es] = ld8u(lV + e * 128 + (((w * 4 + lg) ^ (e & 7)) << 3));
    }
#pragma unroll
    for (int ds = 0; ds < 4; ++ds)
#pragma unroll
      for (int es = 0; es < 4; ++es) acc[ds][es] = mfma16(af[ds], bfv[es], acc[ds][es]);
    __syncthreads();
  }

  zsh[sq][dmy] = zacc;
  for (int wv = 0; wv < 4; ++wv) {
    if (w == wv) {
#pragma unroll
      for (int ds = 0; ds < 4; ++ds)
#pragma unroll
        for (int es = 0; es < 4; ++es)
#pragma unroll
          for (int r = 0; r < 4; ++r) {
            int d = ds * 16 + lg * 4 + r, e = es * 16 + lr;
            if (wv == 0) mbuf[d][e] = acc[ds][es][r];
            else         mbuf[d][e] += acc[ds][es][r];
          }
    }
    __syncthreads();
  }
#pragma unroll
  for (int j = 0; j < 16; ++j) {
    int idx = j * 256 + t;
    Mp[(size_t)bid * 4096 + idx] = mbuf[idx >> 6][idx & 63];
  }
  if (t < 64) zp[(size_t)bid * 64 + t] = zsh[0][t] + zsh[1][t] + zsh[2][t] + zsh[3][t];
}

__global__ __launch_bounds__(256) void k_red(const float* __restrict__ Mp, const float* __restrict__ zp,
                                             u16* __restrict__ Mt, float* __restrict__ zv) {
  const int gh = blockIdx.x;
  const int t = threadIdx.x;
#pragma unroll
  for (int j = 0; j < 16; ++j) {
    int idx = j * 256 + t;
    int d = idx >> 6, e = idx & 63;
    float s = 0.f;
#pragma unroll
    for (int c = 0; c < 8; ++c) s += Mp[(size_t)(gh * 8 + c) * 4096 + idx];
    Mt[(size_t)gh * 4096 + e * 64 + d] = f2bf(s);
  }
  if (t < 64) {
    float s = 0.f;
#pragma unroll
    for (int c = 0; c < 8; ++c) s += zp[(size_t)(gh * 8 + c) * 64 + t];
    zv[gh * 64 + t] = s;
  }
}

// ---------------- fused attention: dbuf K/V + XCD-grouped q-blocks ----------------
// Block remap vb = (bid&7)*256 + (bid>>3): all 4 q-blocks of one (b,h) land on
// ONE XCD, so the 128KB K/V pair is fetched into that XCD's L2 once and re-hit
// by the other 3 q-blocks. stage(0) issued at kernel top (guarded by the
// loop's VMC(4)); zs/lbias writes are barrier'd BEFORE dens reads them
// (R13's race, fixed).

__global__ __launch_bounds__(256, 3) void k_attn(const u16* __restrict__ Q, const u16* __restrict__ K,
                                                 const u16* __restrict__ Vt, const u16* __restrict__ Mt,
                                                 const float* __restrict__ zv, const float* __restrict__ bias,
                                                 const float* __restrict__ beta, u16* __restrict__ blend) {
  __shared__ __align__(16) u16 lK[2][64 * 64];
  __shared__ __align__(16) u16 lV[2][64 * 64];
  __shared__ __align__(16) u16 ps[4][32 * 64];
  __shared__ float lbias[640];
  __shared__ float zs[64];
  __shared__ float rsl[4][32];
  __shared__ float dnl[4][32];

  const int bid = blockIdx.x;
  const int vb = (bid & 7) * 256 + (bid >> 3);   // XCD-grouped remap (2048 = 8*256)
  const int bh = vb >> 2, qg = vb & 3;
  const int b = bh >> 4, h = bh & 15, g = b >> 3;
  const int gh = g * 16 + h;
  const int t = threadIdx.x, lane = t & 63, w = t >> 6;
  const int lr = lane & 15, lg = lane >> 4;
  const int q0w = qg * 128 + w * 32;
  const u16* qp = Q + (size_t)bh * 512 * 64;
  const u16* kp = K + (size_t)bh * 512 * 64;
  const u16* vp = Vt + (size_t)bh * 64 * 512;
  const u16* mp = Mt + (size_t)gh * 4096;
  const float gate = 1.f / (1.f + __expf(-beta[h]));
  u16* psw = &ps[w][0];

  auto stage = [&](int kt, int sl) {
#pragma unroll
    for (int i = 0; i < 2; ++i) {
      int c = w * 128 + i * 64 + lane;
      int kr = c >> 3, u = c & 7;
      async16(&lK[sl][c * 8], kp + (size_t)(kt * 64 + kr) * 64 + ((u ^ (kr & 7)) << 3));
      async16(&lV[sl][c * 8], vp + (size_t)kr * 512 + kt * 64 + ((u ^ (kr & 7)) << 3));
    }
  };

  stage(0, 0);  // issued first; landing guaranteed by the loop's VMC(4)+BARR

  for (int i = t; i < 640; i += 256) lbias[i] = bias[h * 1023 + i + 384 - qg * 128];
  if (t < 64) zs[t] = zv[gh * 64 + t];
  LG0; BARR;  // zs/lbias visible to ALL waves before dens reads zs

  u16x8 qf[2][2];
#pragma unroll
  for (int qs = 0; qs < 2; ++qs)
#pragma unroll
    for (int dc = 0; dc < 2; ++dc)
      qf[qs][dc] = ld8u(qp + (size_t)(q0w + qs * 16 + lr) * 64 + dc * 32 + lg * 8);

#pragma unroll
  for (int qs = 0; qs < 2; ++qs) {
    float sum = 0.f;
#pragma unroll
    for (int dc = 0; dc < 2; ++dc)
#pragma unroll
      for (int j = 0; j < 8; ++j)
        sum += elu1(bf2f(qf[qs][dc][j])) * zs[dc * 32 + lg * 8 + j];
    sum += __shfl_xor(sum, 16, 64);
    sum += __shfl_xor(sum, 32, 64);
    if (lane < 16) dnl[w][qs * 16 + lane] = sum + 1e-6f;
  }

  f32x4 acc[2][4];
#pragma unroll
  for (int qs = 0; qs < 2; ++qs)
#pragma unroll
    for (int es = 0; es < 4; ++es) acc[qs][es] = (f32x4){0.f, 0.f, 0.f, 0.f};
  float rs[2] = {0.f, 0.f};

  for (int kt = 0; kt < 8; ++kt) {
    const int sl = kt & 1;
    if (kt + 1 < 8) stage(kt + 1, sl ^ 1);
    if (kt + 1 < 8) { VMC(4); } else { VMC(0); }
    BARR;

#pragma unroll
    for (int ks = 0; ks < 4; ++ks) {
      const int kr = ks * 16 + lr;
      u16x8 kf0 = ld8u(&lK[sl][kr * 64 + (((0 * 4 + lg) ^ (kr & 7)) << 3)]);
      u16x8 kf1 = ld8u(&lK[sl][kr * 64 + (((1 * 4 + lg) ^ (kr & 7)) << 3)]);
#pragma unroll
      for (int qs = 0; qs < 2; ++qs) {
        f32x4 s = mfma16(kf0, qf[qs][0], (f32x4){0.f, 0.f, 0.f, 0.f});
        s = mfma16(kf1, qf[qs][1], s);
        const int bb = kt * 64 + ks * 16 + lg * 4 - (w * 32 + qs * 16 + lr) + 127;
        u16x4 pk;
        float lsum = 0.f;
#pragma unroll
        for (int r = 0; r < 4; ++r) {
          float p = __expf(s[r] + lbias[bb + r]);
          lsum += p;
          pk[r] = f2bf(p);
        }
        rs[qs] += lsum;
        const int row = qs * 16 + lr;
        const int addr = row * 64 + (((ks * 2 + (lg >> 1)) ^ (row & 7)) << 3) + (lg & 1) * 4;
        *reinterpret_cast<u16x4*>(psw + addr) = pk;
      }
    }
#pragma unroll
    for (int kc = 0; kc < 2; ++kc) {
      u16x8 pf[2];
#pragma unroll
      for (int qs = 0; qs < 2; ++qs) {
        const int row = qs * 16 + lr;
        pf[qs] = ld8u(psw + row * 64 + (((kc * 4 + lg) ^ (row & 7)) << 3));
      }
#pragma unroll
      for (int es = 0; es < 4; ++es) {
        const int er = es * 16 + lr;
        u16x8 vf = ld8u(&lV[sl][er * 64 + (((kc * 4 + lg) ^ (er & 7)) << 3)]);
#pragma unroll
        for (int qs = 0; qs < 2; ++qs) acc[qs][es] = mfma16(pf[qs], vf, acc[qs][es]);
      }
    }
    BARR;
  }

#pragma unroll
  for (int qs = 0; qs < 2; ++qs) {
    float v = rs[qs];
    v += __shfl_xor(v, 16, 64);
    v += __shfl_xor(v, 32, 64);
    if (lane < 16) rsl[w][qs * 16 + lane] = 1.f / v;
  }

  u16x8 sqf[2][2];
#pragma unroll
  for (int qs = 0; qs < 2; ++qs)
#pragma unroll
    for (int dc = 0; dc < 2; ++dc)
#pragma unroll
      for (int j = 0; j < 8; ++j) sqf[qs][dc][j] = f2bf(elu1(bf2f(qf[qs][dc][j])));
  f32x4 am[2][4];
#pragma unroll
  for (int qs = 0; qs < 2; ++qs)
#pragma unroll
    for (int es = 0; es < 4; ++es) am[qs][es] = (f32x4){0.f, 0.f, 0.f, 0.f};
#pragma unroll
  for (int es = 0; es < 4; ++es)
#pragma unroll
    for (int dc = 0; dc < 2; ++dc) {
      u16x8 mf = ld8u(mp + (es * 16 + lr) * 64 + dc * 32 + lg * 8);
#pragma unroll
      for (int qs = 0; qs < 2; ++qs) am[qs][es] = mfma16(sqf[qs][dc], mf, am[qs][es]);
    }

#pragma unroll
  for (int qs = 0; qs < 2; ++qs)
#pragma unroll
    for (int r = 0; r < 4; ++r) {
      const int rowl = qs * 16 + lg * 4 + r;
      const float rinv = rsl[w][rowl];
      const float den = dnl[w][rowl];
      const int q = q0w + rowl;
#pragma unroll
      for (int es = 0; es < 4; ++es) {
        float o = gate * (am[qs][es][r] / den) + (1.f - gate) * acc[qs][es][r] * rinv;
        blend[(size_t)(b * 512 + q) * 1024 + h * 64 + es * 16 + lr] = f2bf(o);
      }
    }
}

// ---------------- launch ----------------

extern "C" void kernel_launch(void* const* d_in, const int* in_sizes, int n_in,
                              void* d_out, int out_size, void* d_ws, size_t ws_size,
                              hipStream_t stream) {
  (void)in_sizes; (void)n_in; (void)out_size; (void)ws_size;
  const float* hs   = (const float*)d_in[0];
  const float* Wq   = (const float*)d_in[1];
  const float* Wk   = (const float*)d_in[2];
  const float* Wv   = (const float*)d_in[3];
  const float* Wo   = (const float*)d_in[4];
  const float* rel  = (const float*)d_in[5];
  const float* beta = (const float*)d_in[6];
  float* out = (float*)d_out;

  char* ws = (char*)d_ws;
  size_t off = 0;
  auto alloc = [&](size_t bytes) -> char* {
    char* p = ws + off;
    off += (bytes + 255) & ~(size_t)255;
    return p;
  };
  u16* hsb    = (u16*)alloc(16384ull * 1024 * 2);  // reused as blend after GEMM1
  u16* wt     = (u16*)alloc(3072ull * 1024 * 2);
  u16* wot    = (u16*)alloc(1024ull * 1024 * 2);
  u16* q      = (u16*)alloc(16384ull * 1024 * 2);
  u16* k      = (u16*)alloc(16384ull * 1024 * 2);
  u16* vt     = (u16*)alloc(16384ull * 1024 * 2);
  float* Mp   = (float*)alloc(512ull * 4096 * 4);
  float* zp   = (float*)alloc(512ull * 64 * 4);
  u16* Mt     = (u16*)alloc(64ull * 4096 * 2);
  float* zv   = (float*)alloc(64ull * 64 * 4);
  float* bias = (float*)alloc(16ull * 1023 * 4);
  u16* blend  = hsb;

  k_cvt<<<8192, 256, 0, stream>>>(hs, hsb);
  k_tr<<<4096, 1024, 0, stream>>>(Wq, Wk, Wv, Wo, wt, wot);
  k_bias<<<4, 256, 0, stream>>>(rel, bias);
  // GEMM1: 128 m-tiles x 12 n-tiles = 1536 blocks
  k_g256<0><<<1536, 512, 0, stream>>>(hsb, wt, q, k, vt, nullptr);
  k_mem<<<512, 256, 0, stream>>>(k, vt, Mp, zp);
  k_red<<<64, 256, 0, stream>>>(Mp, zp, Mt, zv);
  k_attn<<<2048, 256, 0, stream>>>(q, k, vt, Mt, zv, bias, beta, blend);
  // GEMM2: 128 m-tiles x 4 n-tiles = 512 blocks
  k_g256<1><<<512, 512, 0, stream>>>(blend, wot, nullptr, nullptr, nullptr, out);
}

// Round 16
// 331.435 us; speedup vs baseline: 1.0983x; 1.0039x over previous
//
#include <hip/hip_runtime.h>
#include <stdint.h>

typedef unsigned short u16;
typedef u16 u16x8 __attribute__((ext_vector_type(8)));
typedef u16 u16x4 __attribute__((ext_vector_type(4)));
typedef __bf16 bf16x8 __attribute__((ext_vector_type(8)));
typedef float f32x4 __attribute__((ext_vector_type(4)));

#define DEV static __device__ __forceinline__

DEV u16 f2bf(float f) {
  union { float f; uint32_t u; } v; v.f = f;
  uint32_t r = v.u + 0x7FFFu + ((v.u >> 16) & 1u);
  return (u16)(r >> 16);
}
DEV float bf2f(u16 s) {
  union { uint32_t u; float f; } v; v.u = ((uint32_t)s) << 16;
  return v.f;
}
DEV float elu1(float x) { return x > 0.f ? x + 1.f : __expf(x); }
DEV u16x8 ld8u(const u16* p) { return *reinterpret_cast<const u16x8*>(p); }

DEV f32x4 mfma16(u16x8 a, u16x8 b, f32x4 c) {
  return __builtin_amdgcn_mfma_f32_16x16x32_bf16(
      __builtin_bit_cast(bf16x8, a), __builtin_bit_cast(bf16x8, b), c, 0, 0, 0);
}
DEV void async16(void* lds, const void* g) {
  __builtin_amdgcn_global_load_lds(
      (__attribute__((address_space(1))) void*)g,
      (__attribute__((address_space(3))) void*)lds, 16, 0, 0);
}

#define BARR __builtin_amdgcn_s_barrier()
#define LG0  asm volatile("s_waitcnt lgkmcnt(0)" ::: "memory")
#define VMC(N) asm volatile("s_waitcnt vmcnt(" #N ")" ::: "memory")

// ---------------- merged prep kernel: cvt | transpose | bias ----------------

__global__ __launch_bounds__(1024) void k_prep(const float* __restrict__ hs,
                                               const float* __restrict__ Wq, const float* __restrict__ Wk,
                                               const float* __restrict__ Wv, const float* __restrict__ Wo,
                                               const float* __restrict__ rel,
                                               u16* __restrict__ hsb, u16* __restrict__ wt,
                                               u16* __restrict__ wot, float* __restrict__ bias) {
  __shared__ float tb[32][33];
  const int blk = blockIdx.x;
  if (blk < 2048) {
    int i = blk * 1024 + threadIdx.x;
    const float4* p = reinterpret_cast<const float4*>(hs) + (size_t)i * 2;
    float4 a = p[0], bq = p[1];
    u16x8 o;
    o[0] = f2bf(a.x); o[1] = f2bf(a.y); o[2] = f2bf(a.z); o[3] = f2bf(a.w);
    o[4] = f2bf(bq.x); o[5] = f2bf(bq.y); o[6] = f2bf(bq.z); o[7] = f2bf(bq.w);
    reinterpret_cast<u16x8*>(hsb)[i] = o;
  } else if (blk < 6144) {
    const int bid2 = blk - 2048;
    int mat = bid2 >> 10;
    int tile = bid2 & 1023;
    int n0 = (tile >> 5) * 32;
    int k0 = (tile & 31) * 32;
    const float* W = (mat == 0) ? Wq : (mat == 1) ? Wk : (mat == 2) ? Wv : Wo;
    int tx = threadIdx.x & 31, ty = threadIdx.x >> 5;
    tb[ty][tx] = W[(size_t)(k0 + ty) * 1024 + n0 + tx];
    __syncthreads();
    u16 v = f2bf(tb[tx][ty]);
    if (mat < 3) wt[(size_t)(mat * 1024 + n0 + ty) * 1024 + k0 + tx] = v;
    else         wot[(size_t)(n0 + ty) * 1024 + k0 + tx] = v;
  } else {
    int off = threadIdx.x;
    if (off < 1023) {
      int rp = off - 511;
      int bck = rp > 0 ? 16 : 0;
      int arp = rp < 0 ? -rp : rp;
      int idx;
      if (arp < 8) idx = arp;
      else {
        float l = logf((float)arp * 0.125f) / logf(16.0f) * 8.0f;
        int lg = 8 + (int)l;
        idx = lg < 15 ? lg : 15;
      }
      bck += idx;
      for (int h = 0; h < 16; ++h) bias[h * 1023 + off] = rel[bck * 16 + h];
    }
  }
}

// ---------------- 128x256 multi-block MFMA GEMM (R8/R11 core — best measured) ----------------

template <int EPI>
__global__ __launch_bounds__(512, 3) void k_g256(const u16* __restrict__ A, const u16* __restrict__ Bt,
                                                 u16* __restrict__ oq, u16* __restrict__ ok2,
                                                 u16* __restrict__ ovt, float* __restrict__ of) {
  __shared__ __align__(16) u16 lsA[2][128 * 32];
  __shared__ __align__(16) u16 lsB[2][256 * 32];
  const int t = threadIdx.x;
  const int lane = t & 63, w = t >> 6;
  const int wm = w >> 2, wn = w & 3;
  const int lr = lane & 15, lg = lane >> 4;

  const int bid = blockIdx.x;
  const int xcd = bid & 7, local = bid >> 3;
  const int s = local >> 4, w16 = local & 15;
  const int msq = s & 3, nsq = s >> 2;
  const int m0 = (xcd * 16 + msq * 4 + (w16 >> 2)) * 128;
  const int n0 = (nsq * 4 + (w16 & 3)) * 256;

  auto stage = [&](int kt, int slot) {
    const int k0 = kt * 32;
    {
      int c = t, S = c >> 3, q = (c & 7) ^ (S & 7);
      int row = 2 * S + (q >> 2), u = q & 3;
      async16(&lsA[slot][c * 8], A + (size_t)(m0 + row) * 1024 + k0 + u * 8);
    }
#pragma unroll
    for (int i = 0; i < 2; ++i) {
      int c = i * 512 + t, S = c >> 3, q = (c & 7) ^ (S & 7);
      int row = 2 * S + (q >> 2), u = q & 3;
      async16(&lsB[slot][c * 8], Bt + (size_t)(n0 + row) * 1024 + k0 + u * 8);
    }
  };
  auto rdoff = [&](int r_) -> int {
    return (r_ >> 1) * 64 + (((((r_ & 1) << 2) + lg) ^ ((r_ >> 1) & 7)) << 3);
  };

  f32x4 acc[4][4];
#pragma unroll
  for (int i = 0; i < 4; ++i)
#pragma unroll
    for (int j = 0; j < 4; ++j) acc[i][j] = (f32x4){0.f, 0.f, 0.f, 0.f};

  stage(0, 0);
  stage(1, 1);
  VMC(3);
  BARR;

  for (int kt = 0; kt < 32; ++kt) {
    const int slot = kt & 1;
    const u16* la = &lsA[slot][0];
    const u16* lb = &lsB[slot][0];

    u16x8 af[4], bf[4];
#pragma unroll
    for (int mi = 0; mi < 4; ++mi) af[mi] = ld8u(la + rdoff(wm * 64 + mi * 16 + lr));
#pragma unroll
    for (int ni = 0; ni < 4; ++ni) bf[ni] = ld8u(lb + rdoff(wn * 64 + ni * 16 + lr));
    LG0;
    BARR;
    if (kt + 2 < 32) stage(kt + 2, slot);

    __builtin_amdgcn_s_setprio(1);
#pragma unroll
    for (int mi = 0; mi < 4; ++mi)
#pragma unroll
      for (int ni = 0; ni < 4; ++ni)
        acc[mi][ni] = mfma16(af[mi], bf[ni], acc[mi][ni]);
    __builtin_amdgcn_s_setprio(0);

    if (kt + 2 < 32)      { VMC(3); }
    else if (kt == 30)    { VMC(0); }
    BARR;
  }

  if (EPI == 0) {
    const int which = n0 >> 10;
    const int nb = (n0 & 1023) + wn * 64;
#pragma unroll
    for (int mi = 0; mi < 4; ++mi)
#pragma unroll
      for (int r = 0; r < 4; ++r) {
        int m = m0 + wm * 64 + mi * 16 + lg * 4 + r;
        int b = m >> 9, s2 = m & 511;
#pragma unroll
        for (int ni = 0; ni < 4; ++ni) {
          int nc = nb + ni * 16 + lr;
          int h = nc >> 6, d = nc & 63;
          int bh = b * 16 + h;
          u16 v = f2bf(acc[mi][ni][r]);
          if (which == 0)      oq[(size_t)(bh * 512 + s2) * 64 + d] = v;
          else if (which == 1) ok2[(size_t)(bh * 512 + s2) * 64 + d] = v;
          else                 ovt[(size_t)(bh * 64 + d) * 512 + s2] = v;
        }
      }
  } else {
#pragma unroll
    for (int mi = 0; mi < 4; ++mi)
#pragma unroll
      for (int r = 0; r < 4; ++r) {
        int m = m0 + wm * 64 + mi * 16 + lg * 4 + r;
#pragma unroll
        for (int ni = 0; ni < 4; ++ni) {
          int n = n0 + wn * 64 + ni * 16 + lr;
          of[(size_t)m * 1024 + n] = acc[mi][ni][r];
        }
      }
  }
}

// ---------------- compressive memory (MFMA): M = sk^T @ v per (g,h,c) ----------------

__global__ __launch_bounds__(256) void k_mem(const u16* __restrict__ K, const u16* __restrict__ Vt,
                                             float* __restrict__ Mp, float* __restrict__ zp) {
  __shared__ __align__(16) u16 skT[64 * 128];
  __shared__ __align__(16) u16 lV[64 * 128];
  __shared__ float mbuf[64][65];
  __shared__ float zsh[4][64];
  const int bid = blockIdx.x;
  const int g = bid >> 7, h = (bid >> 3) & 15, c = bid & 7;
  const int bh = (g * 8 + c) * 16 + h;
  const u16* kp = K + (size_t)bh * 512 * 64;
  const u16* vp = Vt + (size_t)bh * 64 * 512;
  const int t = threadIdx.x, lane = t & 63, w = t >> 6;
  const int lr = lane & 15, lg = lane >> 4;
  const int dmy = t & 63, sq = t >> 6;

  f32x4 acc[4][4];
#pragma unroll
  for (int i = 0; i < 4; ++i)
#pragma unroll
    for (int j = 0; j < 4; ++j) acc[i][j] = (f32x4){0.f, 0.f, 0.f, 0.f};
  float zacc = 0.f;

  for (int s0 = 0; s0 < 512; s0 += 128) {
#pragma unroll
    for (int i = 0; i < 4; ++i) {
      int c2 = i * 256 + t;
      int row = c2 >> 4, u = c2 & 15;
      async16(lV + c2 * 8, vp + (size_t)row * 512 + s0 + ((u ^ (row & 7)) << 3));
    }
#pragma unroll
    for (int r = 0; r < 4; ++r) {
      const int un = sq + r * 4;
      const int ss0 = un * 8;
      u16x8 vals;
#pragma unroll
      for (int j = 0; j < 8; ++j) {
        float x = elu1(bf2f(kp[(size_t)(s0 + ss0 + j) * 64 + dmy]));
        zacc += x;
        vals[j] = f2bf(x);
      }
      *reinterpret_cast<u16x8*>(skT + dmy * 128 + ((un ^ (dmy & 7)) << 3)) = vals;
    }
    VMC(0);
    __syncthreads();
    u16x8 af[4], bfv[4];
#pragma unroll
    for (int ds = 0; ds < 4; ++ds) {
      const int d = ds * 16 + lr;
      af[ds] = ld8u(skT + d * 128 + (((w * 4 + lg) ^ (d & 7)) << 3));
    }
#pragma unroll
    for (int es = 0; es < 4; ++es) {
      const int e = es * 16 + lr;
      bfv[es] = ld8u(lV + e * 128 + (((w * 4 + lg) ^ (e & 7)) << 3));
    }
#pragma unroll
    for (int ds = 0; ds < 4; ++ds)
#pragma unroll
      for (int es = 0; es < 4; ++es) acc[ds][es] = mfma16(af[ds], bfv[es], acc[ds][es]);
    __syncthreads();
  }

  zsh[sq][dmy] = zacc;
  for (int wv = 0; wv < 4; ++wv) {
    if (w == wv) {
#pragma unroll
      for (int ds = 0; ds < 4; ++ds)
#pragma unroll
        for (int es = 0; es < 4; ++es)
#pragma unroll
          for (int r = 0; r < 4; ++r) {
            int d = ds * 16 + lg * 4 + r, e = es * 16 + lr;
            if (wv == 0) mbuf[d][e] = acc[ds][es][r];
            else         mbuf[d][e] += acc[ds][es][r];
          }
    }
    __syncthreads();
  }
#pragma unroll
  for (int j = 0; j < 16; ++j) {
    int idx = j * 256 + t;
    Mp[(size_t)bid * 4096 + idx] = mbuf[idx >> 6][idx & 63];
  }
  if (t < 64) zp[(size_t)bid * 64 + t] = zsh[0][t] + zsh[1][t] + zsh[2][t] + zsh[3][t];
}

__global__ __launch_bounds__(256) void k_red(const float* __restrict__ Mp, const float* __restrict__ zp,
                                             u16* __restrict__ Mt, float* __restrict__ zv) {
  const int gh = blockIdx.x;
  const int t = threadIdx.x;
#pragma unroll
  for (int j = 0; j < 16; ++j) {
    int idx = j * 256 + t;
    int d = idx >> 6, e = idx & 63;
    float s = 0.f;
#pragma unroll
    for (int c = 0; c < 8; ++c) s += Mp[(size_t)(gh * 8 + c) * 4096 + idx];
    Mt[(size_t)gh * 4096 + e * 64 + d] = f2bf(s);
  }
  if (t < 64) {
    float s = 0.f;
#pragma unroll
    for (int c = 0; c < 8; ++c) s += zp[(size_t)(gh * 8 + c) * 64 + t];
    zv[gh * 64 + t] = s;
  }
}

// ---------------- fused attention: dbuf K/V + XCD-grouped q-blocks ----------------
// Coalesced blend store via obuf (= dead ps buffer); the obuf->global handoff
// is cross-wave, so it needs LG0 (drain ds_writes) BEFORE the barrier (R15's
// bug: raw s_barrier does not drain lgkmcnt, unlike __syncthreads).

__global__ __launch_bounds__(256, 3) void k_attn(const u16* __restrict__ Q, const u16* __restrict__ K,
                                                 const u16* __restrict__ Vt, const u16* __restrict__ Mt,
                                                 const float* __restrict__ zv, const float* __restrict__ bias,
                                                 const float* __restrict__ beta, u16* __restrict__ blend) {
  __shared__ __align__(16) u16 lK[2][64 * 64];
  __shared__ __align__(16) u16 lV[2][64 * 64];
  __shared__ __align__(16) u16 ps[4][32 * 64];
  __shared__ float lbias[640];
  __shared__ float zs[64];
  __shared__ float rsl[4][32];
  __shared__ float dnl[4][32];

  const int bid = blockIdx.x;
  const int vb = (bid & 7) * 256 + (bid >> 3);   // XCD-grouped remap
  const int bh = vb >> 2, qg = vb & 3;
  const int b = bh >> 4, h = bh & 15, g = b >> 3;
  const int gh = g * 16 + h;
  const int t = threadIdx.x, lane = t & 63, w = t >> 6;
  const int lr = lane & 15, lg = lane >> 4;
  const int q0w = qg * 128 + w * 32;
  const u16* qp = Q + (size_t)bh * 512 * 64;
  const u16* kp = K + (size_t)bh * 512 * 64;
  const u16* vp = Vt + (size_t)bh * 64 * 512;
  const u16* mp = Mt + (size_t)gh * 4096;
  const float gate = 1.f / (1.f + __expf(-beta[h]));
  u16* psw = &ps[w][0];

  auto stage = [&](int kt, int sl) {
#pragma unroll
    for (int i = 0; i < 2; ++i) {
      int c = w * 128 + i * 64 + lane;
      int kr = c >> 3, u = c & 7;
      async16(&lK[sl][c * 8], kp + (size_t)(kt * 64 + kr) * 64 + ((u ^ (kr & 7)) << 3));
      async16(&lV[sl][c * 8], vp + (size_t)kr * 512 + kt * 64 + ((u ^ (kr & 7)) << 3));
    }
  };

  stage(0, 0);  // issued first; landing guaranteed by the loop's VMC(4)+BARR

  for (int i = t; i < 640; i += 256) lbias[i] = bias[h * 1023 + i + 384 - qg * 128];
  if (t < 64) zs[t] = zv[gh * 64 + t];
  LG0; BARR;  // zs/lbias visible to ALL waves before dens reads zs

  u16x8 qf[2][2];
#pragma unroll
  for (int qs = 0; qs < 2; ++qs)
#pragma unroll
    for (int dc = 0; dc < 2; ++dc)
      qf[qs][dc] = ld8u(qp + (size_t)(q0w + qs * 16 + lr) * 64 + dc * 32 + lg * 8);

#pragma unroll
  for (int qs = 0; qs < 2; ++qs) {
    float sum = 0.f;
#pragma unroll
    for (int dc = 0; dc < 2; ++dc)
#pragma unroll
      for (int j = 0; j < 8; ++j)
        sum += elu1(bf2f(qf[qs][dc][j])) * zs[dc * 32 + lg * 8 + j];
    sum += __shfl_xor(sum, 16, 64);
    sum += __shfl_xor(sum, 32, 64);
    if (lane < 16) dnl[w][qs * 16 + lane] = sum + 1e-6f;
  }

  f32x4 acc[2][4];
#pragma unroll
  for (int qs = 0; qs < 2; ++qs)
#pragma unroll
    for (int es = 0; es < 4; ++es) acc[qs][es] = (f32x4){0.f, 0.f, 0.f, 0.f};
  float rs[2] = {0.f, 0.f};

  for (int kt = 0; kt < 8; ++kt) {
    const int sl = kt & 1;
    if (kt + 1 < 8) stage(kt + 1, sl ^ 1);
    if (kt + 1 < 8) { VMC(4); } else { VMC(0); }
    BARR;

#pragma unroll
    for (int ks = 0; ks < 4; ++ks) {
      const int kr = ks * 16 + lr;
      u16x8 kf0 = ld8u(&lK[sl][kr * 64 + (((0 * 4 + lg) ^ (kr & 7)) << 3)]);
      u16x8 kf1 = ld8u(&lK[sl][kr * 64 + (((1 * 4 + lg) ^ (kr & 7)) << 3)]);
#pragma unroll
      for (int qs = 0; qs < 2; ++qs) {
        f32x4 s = mfma16(kf0, qf[qs][0], (f32x4){0.f, 0.f, 0.f, 0.f});
        s = mfma16(kf1, qf[qs][1], s);
        const int bb = kt * 64 + ks * 16 + lg * 4 - (w * 32 + qs * 16 + lr) + 127;
        u16x4 pk;
        float lsum = 0.f;
#pragma unroll
        for (int r = 0; r < 4; ++r) {
          float p = __expf(s[r] + lbias[bb + r]);
          lsum += p;
          pk[r] = f2bf(p);
        }
        rs[qs] += lsum;
        const int row = qs * 16 + lr;
        const int addr = row * 64 + (((ks * 2 + (lg >> 1)) ^ (row & 7)) << 3) + (lg & 1) * 4;
        *reinterpret_cast<u16x4*>(psw + addr) = pk;
      }
    }
#pragma unroll
    for (int kc = 0; kc < 2; ++kc) {
      u16x8 pf[2];
#pragma unroll
      for (int qs = 0; qs < 2; ++qs) {
        const int row = qs * 16 + lr;
        pf[qs] = ld8u(psw + row * 64 + (((kc * 4 + lg) ^ (row & 7)) << 3));
      }
#pragma unroll
      for (int es = 0; es < 4; ++es) {
        const int er = es * 16 + lr;
        u16x8 vf = ld8u(&lV[sl][er * 64 + (((kc * 4 + lg) ^ (er & 7)) << 3)]);
#pragma unroll
        for (int qs = 0; qs < 2; ++qs) acc[qs][es] = mfma16(pf[qs], vf, acc[qs][es]);
      }
    }
    BARR;
  }

#pragma unroll
  for (int qs = 0; qs < 2; ++qs) {
    float v = rs[qs];
    v += __shfl_xor(v, 16, 64);
    v += __shfl_xor(v, 32, 64);
    if (lane < 16) rsl[w][qs * 16 + lane] = 1.f / v;
  }

  u16x8 sqf[2][2];
#pragma unroll
  for (int qs = 0; qs < 2; ++qs)
#pragma unroll
    for (int dc = 0; dc < 2; ++dc)
#pragma unroll
      for (int j = 0; j < 8; ++j) sqf[qs][dc][j] = f2bf(elu1(bf2f(qf[qs][dc][j])));
  f32x4 am[2][4];
#pragma unroll
  for (int qs = 0; qs < 2; ++qs)
#pragma unroll
    for (int es = 0; es < 4; ++es) am[qs][es] = (f32x4){0.f, 0.f, 0.f, 0.f};
#pragma unroll
  for (int es = 0; es < 4; ++es)
#pragma unroll
    for (int dc = 0; dc < 2; ++dc) {
      u16x8 mf = ld8u(mp + (es * 16 + lr) * 64 + dc * 32 + lg * 8);
#pragma unroll
      for (int qs = 0; qs < 2; ++qs) am[qs][es] = mfma16(sqf[qs][dc], mf, am[qs][es]);
    }

  // blend -> LDS (ps reused, wave-local region, swizzled u16 writes) ...
  u16* obuf = &ps[0][0];
#pragma unroll
  for (int qs = 0; qs < 2; ++qs)
#pragma unroll
    for (int r = 0; r < 4; ++r) {
      const int rowl = qs * 16 + lg * 4 + r;
      const int rowg = w * 32 + rowl;
      const float rinv = rsl[w][rowl];
      const float den = dnl[w][rowl];
#pragma unroll
      for (int es = 0; es < 4; ++es) {
        float o = gate * (am[qs][es][r] / den) + (1.f - gate) * acc[qs][es][r] * rinv;
        const int unit = es * 2 + (lr >> 3);
        obuf[rowg * 64 + ((unit ^ (rowg & 7)) << 3) + (lr & 7)] = f2bf(o);
      }
    }
  LG0; BARR;  // drain ds_writes BEFORE barrier (cross-wave handoff)
  // ... then coalesced 128B row-segment stores (8 rows x 128B per instruction)
  const int q0blk = qg * 128;
#pragma unroll
  for (int i = 0; i < 4; ++i) {
    const int row = w * 8 + i * 32 + (lane >> 3);
    const int un = lane & 7;
    u16x8 v = ld8u(obuf + row * 64 + ((un ^ (row & 7)) << 3));
    *reinterpret_cast<u16x8*>(blend + (size_t)(b * 512 + q0blk + row) * 1024 + h * 64 + un * 8) = v;
  }
}

// ---------------- launch ----------------

extern "C" void kernel_launch(void* const* d_in, const int* in_sizes, int n_in,
                              void* d_out, int out_size, void* d_ws, size_t ws_size,
                              hipStream_t stream) {
  (void)in_sizes; (void)n_in; (void)out_size; (void)ws_size;
  const float* hs   = (const float*)d_in[0];
  const float* Wq   = (const float*)d_in[1];
  const float* Wk   = (const float*)d_in[2];
  const float* Wv   = (const float*)d_in[3];
  const float* Wo   = (const float*)d_in[4];
  const float* rel  = (const float*)d_in[5];
  const float* beta = (const float*)d_in[6];
  float* out = (float*)d_out;

  char* ws = (char*)d_ws;
  size_t off = 0;
  auto alloc = [&](size_t bytes) -> char* {
    char* p = ws + off;
    off += (bytes + 255) & ~(size_t)255;
    return p;
  };
  u16* hsb    = (u16*)alloc(16384ull * 1024 * 2);  // reused as blend after GEMM1
  u16* wt     = (u16*)alloc(3072ull * 1024 * 2);
  u16* wot    = (u16*)alloc(1024ull * 1024 * 2);
  u16* q      = (u16*)alloc(16384ull * 1024 * 2);
  u16* k      = (u16*)alloc(16384ull * 1024 * 2);
  u16* vt     = (u16*)alloc(16384ull * 1024 * 2);
  float* Mp   = (float*)alloc(512ull * 4096 * 4);
  float* zp   = (float*)alloc(512ull * 64 * 4);
  u16* Mt     = (u16*)alloc(64ull * 4096 * 2);
  float* zv   = (float*)alloc(64ull * 64 * 4);
  float* bias = (float*)alloc(16ull * 1023 * 4);
  u16* blend  = hsb;

  k_prep<<<6145, 1024, 0, stream>>>(hs, Wq, Wk, Wv, Wo, rel, hsb, wt, wot, bias);
  // GEMM1: 128 m-tiles x 12 n-tiles = 1536 blocks
  k_g256<0><<<1536, 512, 0, stream>>>(hsb, wt, q, k, vt, nullptr);
  k_mem<<<512, 256, 0, stream>>>(k, vt, Mp, zp);
  k_red<<<64, 256, 0, stream>>>(Mp, zp, Mt, zv);
  k_attn<<<2048, 256, 0, stream>>>(q, k, vt, Mt, zv, bias, beta, blend);
  // GEMM2: 128 m-tiles x 4 n-tiles = 512 blocks
  k_g256<1><<<512, 512, 0, stream>>>(blend, wot, nullptr, nullptr, nullptr, out);
}